// Round 8
// baseline (286.498 us; speedup 1.0000x reference)
//
#include <hip/hip_runtime.h>

#define IN_C 512
#define OUT_C 1024
#define NC2 2048
#define NEG_SLOPE 0.2f

typedef short frag8 __attribute__((ext_vector_type(8)));
typedef float f32x4 __attribute__((ext_vector_type(4)));

#define GLOAD_LDS16(g, l) __builtin_amdgcn_global_load_lds(\
    (const __attribute__((address_space(1))) void*)(g), \
    (__attribute__((address_space(3))) void*)(l), 16, 0, 0)

__device__ __forceinline__ unsigned short f2b(float f){
  unsigned u = __float_as_uint(f);
  unsigned r = (u + 0x7fffu + ((u >> 16) & 1u)) >> 16;
  return (unsigned short)r;
}
__device__ __forceinline__ float leaky(float v){ return v >= 0.f ? v : NEG_SLOPE * v; }

// ---------------- fused preprocessing (+ counts/cursor/ctrl zeroing) ----------------

__global__ void prep_kernel(const float* __restrict__ W1, const float* __restrict__ W2,
                            const float* __restrict__ Wp1,
                            const float* __restrict__ a_src1, const float* __restrict__ a_dst1,
                            const float* __restrict__ a_src2, const float* __restrict__ a_dst2,
                            unsigned short* __restrict__ WT, unsigned short* __restrict__ Wp1T,
                            float* __restrict__ uv, int* __restrict__ counts,
                            int* __restrict__ cursor, int* __restrict__ ctrl, int N){
  __shared__ float tile[32][33];
  int b = blockIdx.x;
  int tx = threadIdx.x & 31, ty = threadIdx.x >> 5;
  if (b < 1024){
    const float* in = (b >> 9) ? W2 : W1;
    int rowOff = (b >> 9) * OUT_C;
    int bb = b & 511;
    int c0 = (bb & 31) * 32, r0 = (bb >> 5) * 32;
    for (int i = ty; i < 32; i += 8)
      tile[i][tx] = in[(size_t)(r0 + i) * OUT_C + c0 + tx];
    __syncthreads();
    for (int i = ty; i < 32; i += 8)
      WT[(size_t)(c0 + i + rowOff) * IN_C + r0 + tx] = f2b(tile[tx][i]);
  } else if (b < 2048){
    int bb = b - 1024;
    int c0 = (bb & 31) * 32, r0 = (bb >> 5) * 32;
    for (int i = ty; i < 32; i += 8)
      tile[i][tx] = Wp1[(size_t)(r0 + i) * OUT_C + c0 + tx];
    __syncthreads();
    for (int i = ty; i < 32; i += 8)
      Wp1T[(size_t)(c0 + i) * OUT_C + r0 + tx] = f2b(tile[tx][i]);
  } else if (b < 2560){
    int g = (b - 2048) * 4 + (threadIdx.x >> 6);
    int lane = threadIdx.x & 63;
    int which = g >> 9;
    int i = g & 511;
    const float* W = (which < 2) ? W1 : W2;
    const float* a = (which == 0) ? a_src1 : (which == 1) ? a_dst1 : (which == 2) ? a_src2 : a_dst2;
    const float* row = W + (size_t)i * OUT_C;
    float s = 0.f;
    for (int j = lane; j < OUT_C; j += 64) s += row[j] * a[j];
    for (int off = 32; off; off >>= 1) s += __shfl_down(s, off);
    if (lane == 0) uv[which * IN_C + i] = s;
  } else {
    int i = (b - 2560) * 256 + threadIdx.x;
    if (i < N){ counts[i] = 0; cursor[i] = 0; }
    if (b == 2560 && threadIdx.x < 2) ctrl[threadIdx.x] = 0;
  }
}

// ---------------- alpha (packed outputs) + edge histogram folded into same blocks ----

__global__ void alphahist_kernel(const float* __restrict__ x, const float* __restrict__ uv,
                                 const int* __restrict__ dst,
                                 unsigned short* __restrict__ xb,
                                 float2* __restrict__ sa, float2* __restrict__ da,
                                 float2* __restrict__ ese,
                                 int* __restrict__ counts,
                                 float* __restrict__ colsum, float* __restrict__ wv,
                                 int N, int E){
  int n = blockIdx.x;
  int eblocks = (E + 255) / 256;
  // histogram chunk(s) ride along in the first eblocks blocks (grid-stride for safety)
  for (int c = n; c < eblocks; c += N){
    int e = c * 256 + threadIdx.x;
    if (e < E) atomicAdd(&counts[dst[e]], 1);
  }
  int w = threadIdx.x >> 6, lane = threadIdx.x & 63;
  __shared__ float sh[4];
  if (n < 8){
    int i = n * 256 + threadIdx.x;
    if (i < 1024) colsum[i] = 0.f; else wv[i - 1024] = 0.f;
  }
  const float4* rv = (const float4*)(x + (size_t)n * IN_C);
  const float4* un = (const float4*)(uv + w * IN_C);
  float4 v0 = rv[lane], v1 = rv[lane + 64];
  float4 u0 = un[lane], u1 = un[lane + 64];
  float s = v0.x*u0.x + v0.y*u0.y + v0.z*u0.z + v0.w*u0.w
          + v1.x*u1.x + v1.y*u1.y + v1.z*u1.z + v1.w*u1.w;
  if (w == 0){
    ushort4 p0, p1;
    p0.x = f2b(v0.x); p0.y = f2b(v0.y); p0.z = f2b(v0.z); p0.w = f2b(v0.w);
    p1.x = f2b(v1.x); p1.y = f2b(v1.y); p1.z = f2b(v1.z); p1.w = f2b(v1.w);
    *(ushort4*)(xb + (size_t)n * IN_C + lane * 4) = p0;
    *(ushort4*)(xb + (size_t)n * IN_C + 256 + lane * 4) = p1;
  }
  for (int off = 32; off; off >>= 1) s += __shfl_down(s, off);
  if (lane == 0) sh[w] = s;
  __syncthreads();
  if (threadIdx.x == 0){
    float2 vsa; vsa.x = sh[0]; vsa.y = sh[2];
    float2 vda; vda.x = sh[1]; vda.y = sh[3];
    sa[n] = vsa; da[n] = vda;
    float2 es;                               // max-free softmax validated R6
    es.x = expf(leaky(sh[0] + sh[1]));
    es.y = expf(leaky(sh[2] + sh[3]));
    ese[n] = es;
  }
}

// ---------------- scan + CSR scatter in ONE dispatch ----------------
// Block 0 scans counts->offs with 1024 threads, release-stores ctrl[0]=1; all
// blocks (all-resident: ~157 blocks << capacity) acquire-spin, then scatter.

__global__ __launch_bounds__(1024) void scancsr_kernel(const int* __restrict__ counts,
                                                       int* __restrict__ offs,
                                                       const int* __restrict__ src,
                                                       const int* __restrict__ dst,
                                                       int* cursor, int* __restrict__ nsrc,
                                                       int* ctrl, int N, int E){
  int tid = threadIdx.x, lane = tid & 63, wave = tid >> 6;
  if (blockIdx.x == 0){
    __shared__ int ws[16];
    __shared__ int base_s;
    if (tid == 0) base_s = 0;
    __syncthreads();
    for (int base = 0; base < N; base += 1024){
      int i = base + tid;
      int v = (i < N) ? counts[i] : 0;
      int sc = v;
      for (int o = 1; o < 64; o <<= 1){
        int t = __shfl_up(sc, o);
        if (lane >= o) sc += t;
      }
      if (lane == 63) ws[wave] = sc;
      __syncthreads();
      int wp = 0, tot = 0;
#pragma unroll
      for (int k = 0; k < 16; k++){ int w_ = ws[k]; if (k < wave) wp += w_; tot += w_; }
      if (i < N) offs[i] = base_s + wp + sc - v;
      __syncthreads();
      if (tid == 0) base_s += tot;
      __syncthreads();
    }
    if (tid == 0){
      __threadfence();
      __hip_atomic_store(&ctrl[0], 1, __ATOMIC_RELEASE, __HIP_MEMORY_SCOPE_AGENT);
    }
  }
  if (tid == 0){
    while (__hip_atomic_load(&ctrl[0], __ATOMIC_ACQUIRE, __HIP_MEMORY_SCOPE_AGENT) == 0){}
  }
  __syncthreads();
  int e = blockIdx.x * 1024 + tid;
  if (e < E){
    int d = dst[e];
    int p = atomicAdd(&cursor[d], 1);
    nsrc[offs[d] + p] = src[e];
  }
}

// ---------------- aggregate-first: wave-per-dst, unpack-once inner loop ----------

__global__ __launch_bounds__(256) void aggx_kernel(
    const int* __restrict__ counts, const int* __restrict__ offs,
    const int* __restrict__ nsrc,
    const float2* __restrict__ sa, const float2* __restrict__ da,
    const float2* __restrict__ ese,
    const unsigned short* __restrict__ xb,
    unsigned short* __restrict__ xa1b, unsigned short* __restrict__ xa2b, int N){
  int wid = threadIdx.x >> 6, lane = threadIdx.x & 63;
  int d = blockIdx.x * 4 + wid;
  if (d >= N) return;
  float2 dad = da[d];
  int deg = counts[d], off = offs[d];
  float acc1[8] = {0,0,0,0,0,0,0,0}, acc2[8] = {0,0,0,0,0,0,0,0};
  float den1 = 0.f, den2 = 0.f;
  const unsigned short* Xb = xb + lane * 8;
  for (int base = 0; base < deg; base += 64){
    int i = base + lane;
    int s = 0; float x1 = 0.f, x2 = 0.f;
    if (i < deg){
      s = nsrc[off + i];
      float2 sas = sa[s];
      x1 = expf(leaky(sas.x + dad.x));
      x2 = expf(leaky(sas.y + dad.y));
    }
    den1 += x1; den2 += x2;
    int cnt = min(64, deg - base);
#pragma unroll 4
    for (int j = 0; j < cnt; j++){
      int sj = __shfl(s, j);
      float w1j = __shfl(x1, j);
      float w2j = __shfl(x2, j);
      int4 u = *(const int4*)(Xb + (size_t)sj * IN_C);
      float f[8];
      f[0] = __uint_as_float(((unsigned)u.x) << 16);
      f[1] = __uint_as_float(((unsigned)u.x) & 0xffff0000u);
      f[2] = __uint_as_float(((unsigned)u.y) << 16);
      f[3] = __uint_as_float(((unsigned)u.y) & 0xffff0000u);
      f[4] = __uint_as_float(((unsigned)u.z) << 16);
      f[5] = __uint_as_float(((unsigned)u.z) & 0xffff0000u);
      f[6] = __uint_as_float(((unsigned)u.w) << 16);
      f[7] = __uint_as_float(((unsigned)u.w) & 0xffff0000u);
#pragma unroll
      for (int c = 0; c < 8; c++){ acc1[c] += w1j * f[c]; acc2[c] += w2j * f[c]; }
    }
  }
  for (int o = 32; o; o >>= 1){
    den1 += __shfl_xor(den1, o);
    den2 += __shfl_xor(den2, o);
  }
  float2 es = ese[d];
  {
    int4 u = *(const int4*)(Xb + (size_t)d * IN_C);
    float f[8];
    f[0] = __uint_as_float(((unsigned)u.x) << 16);
    f[1] = __uint_as_float(((unsigned)u.x) & 0xffff0000u);
    f[2] = __uint_as_float(((unsigned)u.y) << 16);
    f[3] = __uint_as_float(((unsigned)u.y) & 0xffff0000u);
    f[4] = __uint_as_float(((unsigned)u.z) << 16);
    f[5] = __uint_as_float(((unsigned)u.z) & 0xffff0000u);
    f[6] = __uint_as_float(((unsigned)u.w) << 16);
    f[7] = __uint_as_float(((unsigned)u.w) & 0xffff0000u);
#pragma unroll
    for (int c = 0; c < 8; c++){ acc1[c] += es.x * f[c]; acc2[c] += es.y * f[c]; }
  }
  den1 += es.x; den2 += es.y;
  float inv1 = 1.f / den1, inv2 = 1.f / den2;
  size_t outb = (size_t)d * IN_C + lane * 8;
  int4 o1, o2;
  o1.x = (int)((unsigned)f2b(acc1[0]*inv1) | ((unsigned)f2b(acc1[1]*inv1) << 16));
  o1.y = (int)((unsigned)f2b(acc1[2]*inv1) | ((unsigned)f2b(acc1[3]*inv1) << 16));
  o1.z = (int)((unsigned)f2b(acc1[4]*inv1) | ((unsigned)f2b(acc1[5]*inv1) << 16));
  o1.w = (int)((unsigned)f2b(acc1[6]*inv1) | ((unsigned)f2b(acc1[7]*inv1) << 16));
  o2.x = (int)((unsigned)f2b(acc2[0]*inv2) | ((unsigned)f2b(acc2[1]*inv2) << 16));
  o2.y = (int)((unsigned)f2b(acc2[2]*inv2) | ((unsigned)f2b(acc2[3]*inv2) << 16));
  o2.z = (int)((unsigned)f2b(acc2[4]*inv2) | ((unsigned)f2b(acc2[5]*inv2) << 16));
  o2.w = (int)((unsigned)f2b(acc2[6]*inv2) | ((unsigned)f2b(acc2[7]*inv2) << 16));
  *(int4*)(xa1b + outb) = o1;
  *(int4*)(xa2b + outb) = o2;
}

// ---------------- fused GEMM-H: exact R0 structure (frozen; best measured) -------

__global__ __launch_bounds__(256) void gemmh_kernel(const unsigned short* __restrict__ A1,
                                                    const unsigned short* __restrict__ A2,
                                                    const unsigned short* __restrict__ BT,
                                                    const float* __restrict__ b1,
                                                    const float* __restrict__ b2,
                                                    const float* __restrict__ prelu_a,
                                                    unsigned short* __restrict__ hsum,
                                                    unsigned short* __restrict__ hdiff,
                                                    int M, int Mtiles, int perx){
  const int bid = blockIdx.x;
  const int xcd = bid & 7;
  const int li = bid >> 3;
  const int bn_t = li & 7;
  const int bm_t = xcd * perx + (li >> 3);
  if (bm_t >= Mtiles) return;
  const int bm = bm_t * 64, bn = bn_t * 128;
  __shared__ unsigned short Al[64 * 32];   // 4 KB
  __shared__ unsigned short Bl[128 * 32];  // 8 KB
  const int t = threadIdx.x;
  const int lane = t & 63, wid = t >> 6;
  const int wj = wid;
  const int l16 = lane & 15, q = lane >> 4;
  const int lch = (lane & 3) * 8;
  f32x4 acc1[4][2] = {};
  f32x4 acc2[4][2] = {};
  const int arow = bm + wid * 16 + (lane >> 2);
  const int brow0 = bn + wid * 32 + (lane >> 2);
  const int ga = min(arow, M - 1);
  const unsigned short* pa1 = A1 + (size_t)ga * IN_C + lch;
  const unsigned short* pa2 = A2 + (size_t)ga * IN_C + lch;
  const unsigned short* pb0 = BT + (size_t)brow0 * IN_C + lch;
  const unsigned short* pb1 = BT + (size_t)(brow0 + 16) * IN_C + lch;
  const size_t boff2 = (size_t)OUT_C * IN_C;
  // ---- GEMM 1 ----
  for (int k0 = 0; k0 < IN_C; k0 += 32){
    GLOAD_LDS16(pa1 + k0, &Al[(wid * 16) * 32]);
    GLOAD_LDS16(pb0 + k0, &Bl[(wid * 32) * 32]);
    GLOAD_LDS16(pb1 + k0, &Bl[(wid * 32 + 16) * 32]);
    __syncthreads();
    frag8 af[4], bf[2];
#pragma unroll
    for (int mi = 0; mi < 4; mi++) af[mi] = *(const frag8*)&Al[(mi*16 + l16) * 32 + q*8];
#pragma unroll
    for (int nj = 0; nj < 2; nj++) bf[nj] = *(const frag8*)&Bl[(wj*32 + nj*16 + l16) * 32 + q*8];
#pragma unroll
    for (int mi = 0; mi < 4; mi++)
#pragma unroll
      for (int nj = 0; nj < 2; nj++)
        acc1[mi][nj] = __builtin_amdgcn_mfma_f32_16x16x32_bf16(af[mi], bf[nj], acc1[mi][nj], 0, 0, 0);
    __syncthreads();
  }
  // ---- GEMM 2 ----
  for (int k0 = 0; k0 < IN_C; k0 += 32){
    GLOAD_LDS16(pa2 + k0, &Al[(wid * 16) * 32]);
    GLOAD_LDS16(pb0 + boff2 + k0, &Bl[(wid * 32) * 32]);
    GLOAD_LDS16(pb1 + boff2 + k0, &Bl[(wid * 32 + 16) * 32]);
    __syncthreads();
    frag8 af[4], bf[2];
#pragma unroll
    for (int mi = 0; mi < 4; mi++) af[mi] = *(const frag8*)&Al[(mi*16 + l16) * 32 + q*8];
#pragma unroll
    for (int nj = 0; nj < 2; nj++) bf[nj] = *(const frag8*)&Bl[(wj*32 + nj*16 + l16) * 32 + q*8];
#pragma unroll
    for (int mi = 0; mi < 4; mi++)
#pragma unroll
      for (int nj = 0; nj < 2; nj++)
        acc2[mi][nj] = __builtin_amdgcn_mfma_f32_16x16x32_bf16(af[mi], bf[nj], acc2[mi][nj], 0, 0, 0);
    __syncthreads();
  }
  float pa = prelu_a[0];
#pragma unroll
  for (int mi = 0; mi < 4; mi++){
#pragma unroll
    for (int r = 0; r < 4; r++){
      int row = bm + mi*16 + q*4 + r;
      if (row >= M) continue;
#pragma unroll
      for (int nj = 0; nj < 2; nj++){
        int col = bn + wj*32 + nj*16 + l16;
        float v1 = acc1[mi][nj][r] + b1[col];
        v1 = v1 >= 0.f ? v1 : pa * v1;
        float v2 = acc2[mi][nj][r] + b2[col];
        v2 = v2 >= 0.f ? v2 : pa * v2;
        size_t idx = (size_t)row * OUT_C + col;
        hsum[idx]  = f2b(v1 + v2);
        hdiff[idx] = f2b(v1 - v2);
      }
    }
  }
}

// ---------------- GEMM2: exact R0 structure (frozen) ----------------

__global__ __launch_bounds__(256) void gemm2_kernel(const unsigned short* __restrict__ A,
                                                    const unsigned short* __restrict__ BT,
                                                    const float* __restrict__ bp1,
                                                    float* __restrict__ colsum,
                                                    int M, int Mtiles, int perx){
  const int bid = blockIdx.x;
  const int xcd = bid & 7;
  const int li = bid >> 3;
  const int bn_t = li & 7;
  const int bm_t = xcd * perx + (li >> 3);
  if (bm_t >= Mtiles) return;
  const int bm = bm_t * 64, bn = bn_t * 128;
  __shared__ unsigned short Al[64 * 32];
  __shared__ unsigned short Bl[128 * 32];
  __shared__ float cs[128];
  const int t = threadIdx.x;
  const int lane = t & 63, wid = t >> 6;
  const int wj = wid;
  const int l16 = lane & 15, q = lane >> 4;
  const int lch = (lane & 3) * 8;
  if (t < 128) cs[t] = 0.f;
  f32x4 acc[4][2] = {};
  const int arow = bm + wid * 16 + (lane >> 2);
  const int brow0 = bn + wid * 32 + (lane >> 2);
  const int ga = min(arow, M - 1);
  const unsigned short* pa = A + (size_t)ga * OUT_C + lch;
  const unsigned short* pb0 = BT + (size_t)brow0 * OUT_C + lch;
  const unsigned short* pb1 = BT + (size_t)(brow0 + 16) * OUT_C + lch;
  for (int k0 = 0; k0 < OUT_C; k0 += 32){
    GLOAD_LDS16(pa + k0, &Al[(wid * 16) * 32]);
    GLOAD_LDS16(pb0 + k0, &Bl[(wid * 32) * 32]);
    GLOAD_LDS16(pb1 + k0, &Bl[(wid * 32 + 16) * 32]);
    __syncthreads();
    frag8 af[4], bf[2];
#pragma unroll
    for (int mi = 0; mi < 4; mi++) af[mi] = *(const frag8*)&Al[(mi*16 + l16) * 32 + q*8];
#pragma unroll
    for (int nj = 0; nj < 2; nj++) bf[nj] = *(const frag8*)&Bl[(wj*32 + nj*16 + l16) * 32 + q*8];
#pragma unroll
    for (int mi = 0; mi < 4; mi++)
#pragma unroll
      for (int nj = 0; nj < 2; nj++)
        acc[mi][nj] = __builtin_amdgcn_mfma_f32_16x16x32_bf16(af[mi], bf[nj], acc[mi][nj], 0, 0, 0);
    __syncthreads();
  }
#pragma unroll
  for (int nj = 0; nj < 2; nj++){
    int col = bn + wj*32 + nj*16 + l16;
    float bias = bp1[col];
    float p = 0.f;
#pragma unroll
    for (int mi = 0; mi < 4; mi++){
#pragma unroll
      for (int r = 0; r < 4; r++){
        int row = bm + mi*16 + q*4 + r;
        float tv = tanhf(acc[mi][nj][r] + bias);
        if (row < M) p += tv;
      }
    }
    p += __shfl_xor(p, 16);
    p += __shfl_xor(p, 32);
    if (q == 0) atomicAdd(&cs[wj*32 + nj*16 + l16], p);
  }
  __syncthreads();
  if (t < 128) atomicAdd(&colsum[bn + t], cs[t]);
}

// ---------------- wproj + softmax fused (last-block-ticket) ----------------

__global__ void wprojsm_kernel(const float* __restrict__ colsum, const float* __restrict__ Wp2,
                               float* __restrict__ wv, float* __restrict__ att,
                               int* ctrl, float invN){
  int o = blockIdx.x * 256 + threadIdx.x;
  int c0 = blockIdx.y * 128;
  float acc = 0.f;
  for (int c = c0; c < c0 + 128; c++) acc += colsum[c] * Wp2[(size_t)c * OUT_C + o];
  atomicAdd(&wv[o], acc);
  // last of the 32 blocks runs the 1024-wide softmax
  __threadfence();
  __shared__ int amlast;
  __shared__ float red[256];
  if (threadIdx.x == 0)
    amlast = (atomicAdd(&ctrl[1], 1) == gridDim.x * gridDim.y - 1) ? 1 : 0;
  __syncthreads();
  if (!amlast) return;
  __threadfence();
  int t = threadIdx.x;
  float w0 = wv[t] * invN, w1 = wv[t + 256] * invN,
        w2 = wv[t + 512] * invN, w3 = wv[t + 768] * invN;
  float m = fmaxf(fmaxf(w0, w1), fmaxf(w2, w3));
  red[t] = m; __syncthreads();
  for (int s = 128; s > 0; s >>= 1){ if (t < s) red[t] = fmaxf(red[t], red[t + s]); __syncthreads(); }
  m = red[0]; __syncthreads();
  float e0 = expf(w0 - m), e1 = expf(w1 - m), e2 = expf(w2 - m), e3 = expf(w3 - m);
  red[t] = e0 + e1 + e2 + e3; __syncthreads();
  for (int s = 128; s > 0; s >>= 1){ if (t < s) red[t] += red[t + s]; __syncthreads(); }
  float inv = 1.f / red[0];
  att[t] = e0 * inv; att[t + 256] = e1 * inv; att[t + 512] = e2 * inv; att[t + 768] = e3 * inv;
}

__global__ void combine_kernel(const float* __restrict__ att, const unsigned short* __restrict__ hs,
                               const unsigned short* __restrict__ hd, float* __restrict__ out, int total8){
  int i = blockIdx.x * 256 + threadIdx.x;
  if (i >= total8) return;
  int colb = (i & 127) * 8;
  int4 us = ((const int4*)hs)[i];
  int4 ud = ((const int4*)hd)[i];
  float4 a0 = *(const float4*)(att + colb);
  float4 a1 = *(const float4*)(att + colb + 4);
  float o[8]; float sv, dv;
  sv = __uint_as_float(((unsigned)us.x) << 16);        dv = __uint_as_float(((unsigned)ud.x) << 16);
  o[0] = 0.5f * sv + (a0.x - 0.5f) * dv;
  sv = __uint_as_float(((unsigned)us.x) & 0xffff0000u); dv = __uint_as_float(((unsigned)ud.x) & 0xffff0000u);
  o[1] = 0.5f * sv + (a0.y - 0.5f) * dv;
  sv = __uint_as_float(((unsigned)us.y) << 16);        dv = __uint_as_float(((unsigned)ud.y) << 16);
  o[2] = 0.5f * sv + (a0.z - 0.5f) * dv;
  sv = __uint_as_float(((unsigned)us.y) & 0xffff0000u); dv = __uint_as_float(((unsigned)ud.y) & 0xffff0000u);
  o[3] = 0.5f * sv + (a0.w - 0.5f) * dv;
  sv = __uint_as_float(((unsigned)us.z) << 16);        dv = __uint_as_float(((unsigned)ud.z) << 16);
  o[4] = 0.5f * sv + (a1.x - 0.5f) * dv;
  sv = __uint_as_float(((unsigned)us.z) & 0xffff0000u); dv = __uint_as_float(((unsigned)ud.z) & 0xffff0000u);
  o[5] = 0.5f * sv + (a1.y - 0.5f) * dv;
  sv = __uint_as_float(((unsigned)us.w) << 16);        dv = __uint_as_float(((unsigned)ud.w) << 16);
  o[6] = 0.5f * sv + (a1.z - 0.5f) * dv;
  sv = __uint_as_float(((unsigned)us.w) & 0xffff0000u); dv = __uint_as_float(((unsigned)ud.w) & 0xffff0000u);
  o[7] = 0.5f * sv + (a1.w - 0.5f) * dv;
  float4 f0; f0.x = o[0]; f0.y = o[1]; f0.z = o[2]; f0.w = o[3];
  float4 f1; f1.x = o[4]; f1.y = o[5]; f1.z = o[6]; f1.w = o[7];
  *(float4*)(out + (size_t)i * 8) = f0;
  *(float4*)(out + (size_t)i * 8 + 4) = f1;
}

// ---------------- launch ----------------

extern "C" void kernel_launch(void* const* d_in, const int* in_sizes, int n_in,
                              void* d_out, int out_size, void* d_ws, size_t ws_size,
                              hipStream_t stream){
  const float* x      = (const float*)d_in[0];
  const int*   edge   = (const int*)d_in[1];
  const float* W1     = (const float*)d_in[2];
  const float* a_src1 = (const float*)d_in[3];
  const float* a_dst1 = (const float*)d_in[4];
  const float* b1     = (const float*)d_in[5];
  const float* W2     = (const float*)d_in[6];
  const float* a_src2 = (const float*)d_in[7];
  const float* a_dst2 = (const float*)d_in[8];
  const float* b2     = (const float*)d_in[9];
  const float* prelu_a= (const float*)d_in[10];
  const float* Wp1    = (const float*)d_in[11];
  const float* bp1    = (const float*)d_in[12];
  const float* Wp2    = (const float*)d_in[13];
  const int N = in_sizes[0] / IN_C;
  const int E = in_sizes[1] / 2;
  const int* srcArr = edge;
  const int* dstArr = edge + E;

  char* ws = (char*)d_ws;
  size_t o = 0;
  auto alloc = [&](size_t b) -> char* {
    char* p = ws + o;
    o = (o + b + 255) & ~(size_t)255;
    return p;
  };
  unsigned short* xb    = (unsigned short*)alloc((size_t)N * IN_C * 2);
  unsigned short* WT    = (unsigned short*)alloc((size_t)NC2 * IN_C * 2);
  unsigned short* Wp1T  = (unsigned short*)alloc((size_t)OUT_C * OUT_C * 2);
  unsigned short* xa1b  = (unsigned short*)alloc((size_t)N * IN_C * 2);
  unsigned short* xa2b  = (unsigned short*)alloc((size_t)N * IN_C * 2);
  unsigned short* hsum  = (unsigned short*)alloc((size_t)N * OUT_C * 2);
  unsigned short* hdiff = (unsigned short*)alloc((size_t)N * OUT_C * 2);
  float*          uv    = (float*)alloc(4 * IN_C * 4);
  float2*         sa    = (float2*)alloc((size_t)N * 8);
  float2*         da    = (float2*)alloc((size_t)N * 8);
  float2*         ese   = (float2*)alloc((size_t)N * 8);
  int*            counts= (int*)alloc((size_t)N * 4);
  int*            offs  = (int*)alloc((size_t)(N + 1) * 4);
  int*            cursor= (int*)alloc((size_t)N * 4);
  int*            ctrl  = (int*)alloc(2 * 4);
  int*            nsrc  = (int*)alloc((size_t)E * 4);
  float*          colsum= (float*)alloc(OUT_C * 4);
  float*          wv    = (float*)alloc(OUT_C * 4);
  float*          att   = (float*)alloc(OUT_C * 4);

  const int Mtiles = (N + 63) / 64;
  const int perx = (Mtiles + 7) / 8;
  const int gemmgrid = 8 * perx * 8;
  const int zblocks = (N + 255) / 256;
  const int sblocks = (E + 1023) / 1024;

  prep_kernel<<<2560 + zblocks, 256, 0, stream>>>(W1, W2, Wp1, a_src1, a_dst1, a_src2, a_dst2,
                                                  WT, Wp1T, uv, counts, cursor, ctrl, N);
  alphahist_kernel<<<N, 256, 0, stream>>>(x, uv, dstArr, xb, sa, da, ese,
                                          counts, colsum, wv, N, E);
  scancsr_kernel<<<sblocks, 1024, 0, stream>>>(counts, offs, srcArr, dstArr, cursor, nsrc,
                                               ctrl, N, E);
  aggx_kernel<<<(N + 3) / 4, 256, 0, stream>>>(counts, offs, nsrc, sa, da, ese,
                                               xb, xa1b, xa2b, N);
  gemmh_kernel<<<gemmgrid, 256, 0, stream>>>(xa1b, xa2b, WT, b1, b2, prelu_a,
                                             hsum, hdiff, N, Mtiles, perx);
  gemm2_kernel<<<gemmgrid, 256, 0, stream>>>(hsum, Wp1T, bp1, colsum, N, Mtiles, perx);
  wprojsm_kernel<<<dim3(4, 8), 256, 0, stream>>>(colsum, Wp2, wv, att, ctrl, 1.0f / (float)N);
  combine_kernel<<<(N * OUT_C / 8 + 255) / 256, 256, 0, stream>>>(att, hsum, hdiff, (float*)d_out,
                                                                  N * OUT_C / 8);
}

// Round 13
// 278.093 us; speedup vs baseline: 1.0302x; 1.0302x over previous
//
#include <hip/hip_runtime.h>

#define IN_C 512
#define OUT_C 1024
#define NC2 2048
#define NEG_SLOPE 0.2f

typedef short frag8 __attribute__((ext_vector_type(8)));
typedef float f32x4 __attribute__((ext_vector_type(4)));
typedef int i32x4 __attribute__((ext_vector_type(4)));

#define GLOAD_LDS16(g, l) __builtin_amdgcn_global_load_lds(\
    (const __attribute__((address_space(1))) void*)(g), \
    (__attribute__((address_space(3))) void*)(l), 16, 0, 0)

__device__ __forceinline__ unsigned short f2b(float f){
  unsigned u = __float_as_uint(f);
  unsigned r = (u + 0x7fffu + ((u >> 16) & 1u)) >> 16;
  return (unsigned short)r;
}
__device__ __forceinline__ float leaky(float v){ return v >= 0.f ? v : NEG_SLOPE * v; }

// ---------------- fused preprocessing (+ counts/cursor zeroing) ----------------

__global__ void prep_kernel(const float* __restrict__ W1, const float* __restrict__ W2,
                            const float* __restrict__ Wp1,
                            const float* __restrict__ a_src1, const float* __restrict__ a_dst1,
                            const float* __restrict__ a_src2, const float* __restrict__ a_dst2,
                            unsigned short* __restrict__ WT, unsigned short* __restrict__ Wp1T,
                            float* __restrict__ uv, int* __restrict__ counts,
                            int* __restrict__ cursor, int N){
  __shared__ float tile[32][33];
  int b = blockIdx.x;
  int tx = threadIdx.x & 31, ty = threadIdx.x >> 5;
  if (b < 1024){
    const float* in = (b >> 9) ? W2 : W1;
    int rowOff = (b >> 9) * OUT_C;
    int bb = b & 511;
    int c0 = (bb & 31) * 32, r0 = (bb >> 5) * 32;
    for (int i = ty; i < 32; i += 8)
      tile[i][tx] = in[(size_t)(r0 + i) * OUT_C + c0 + tx];
    __syncthreads();
    for (int i = ty; i < 32; i += 8)
      WT[(size_t)(c0 + i + rowOff) * IN_C + r0 + tx] = f2b(tile[tx][i]);
  } else if (b < 2048){
    int bb = b - 1024;
    int c0 = (bb & 31) * 32, r0 = (bb >> 5) * 32;
    for (int i = ty; i < 32; i += 8)
      tile[i][tx] = Wp1[(size_t)(r0 + i) * OUT_C + c0 + tx];
    __syncthreads();
    for (int i = ty; i < 32; i += 8)
      Wp1T[(size_t)(c0 + i) * OUT_C + r0 + tx] = f2b(tile[tx][i]);
  } else if (b < 2560){
    int g = (b - 2048) * 4 + (threadIdx.x >> 6);
    int lane = threadIdx.x & 63;
    int which = g >> 9;
    int i = g & 511;
    const float* W = (which < 2) ? W1 : W2;
    const float* a = (which == 0) ? a_src1 : (which == 1) ? a_dst1 : (which == 2) ? a_src2 : a_dst2;
    const float* row = W + (size_t)i * OUT_C;
    float s = 0.f;
    for (int j = lane; j < OUT_C; j += 64) s += row[j] * a[j];
    for (int off = 32; off; off >>= 1) s += __shfl_down(s, off);
    if (lane == 0) uv[which * IN_C + i] = s;
  } else {
    int i = (b - 2560) * 256 + threadIdx.x;
    if (i < N){ counts[i] = 0; cursor[i] = 0; }
  }
}

// ---------------- alpha (packed outputs) + edge histogram as tail blocks ----------

__global__ void alphahist_kernel(const float* __restrict__ x, const float* __restrict__ uv,
                                 const int* __restrict__ dst,
                                 unsigned short* __restrict__ xb,
                                 float2* __restrict__ sa, float2* __restrict__ da,
                                 float2* __restrict__ ese,
                                 int* __restrict__ counts,
                                 float* __restrict__ colsum, float* __restrict__ wv,
                                 int N, int E){
  int b = blockIdx.x;
  if (b >= N){
    int e = (b - N) * 256 + threadIdx.x;
    if (e < E) atomicAdd(&counts[dst[e]], 1);
    return;
  }
  int n = b;
  int w = threadIdx.x >> 6, lane = threadIdx.x & 63;
  __shared__ float sh[4];
  if (n < 8){
    int i = n * 256 + threadIdx.x;
    if (i < 1024) colsum[i] = 0.f; else wv[i - 1024] = 0.f;
  }
  const float4* rv = (const float4*)(x + (size_t)n * IN_C);
  const float4* un = (const float4*)(uv + w * IN_C);
  float4 v0 = rv[lane], v1 = rv[lane + 64];
  float4 u0 = un[lane], u1 = un[lane + 64];
  float s = v0.x*u0.x + v0.y*u0.y + v0.z*u0.z + v0.w*u0.w
          + v1.x*u1.x + v1.y*u1.y + v1.z*u1.z + v1.w*u1.w;
  if (w == 0){
    ushort4 p0, p1;
    p0.x = f2b(v0.x); p0.y = f2b(v0.y); p0.z = f2b(v0.z); p0.w = f2b(v0.w);
    p1.x = f2b(v1.x); p1.y = f2b(v1.y); p1.z = f2b(v1.z); p1.w = f2b(v1.w);
    *(ushort4*)(xb + (size_t)n * IN_C + lane * 4) = p0;
    *(ushort4*)(xb + (size_t)n * IN_C + 256 + lane * 4) = p1;
  }
  for (int off = 32; off; off >>= 1) s += __shfl_down(s, off);
  if (lane == 0) sh[w] = s;
  __syncthreads();
  if (threadIdx.x == 0){
    float2 vsa; vsa.x = sh[0]; vsa.y = sh[2];
    float2 vda; vda.x = sh[1]; vda.y = sh[3];
    sa[n] = vsa; da[n] = vda;
    float2 es;                               // max-free softmax validated R6
    es.x = expf(leaky(sh[0] + sh[1]));
    es.y = expf(leaky(sh[2] + sh[3]));
    ese[n] = es;
  }
}

// ---------------- single-block scan ----------------

__global__ __launch_bounds__(1024) void scan_kernel(const int* __restrict__ counts,
                                                    int* __restrict__ offs, int n){
  __shared__ int ws[16];
  __shared__ int base_s;
  int tid = threadIdx.x, lane = tid & 63, wave = tid >> 6;
  if (tid == 0) base_s = 0;
  __syncthreads();
  for (int base = 0; base < n; base += 1024){
    int i = base + tid;
    int v = (i < n) ? counts[i] : 0;
    int sc = v;
    for (int o = 1; o < 64; o <<= 1){
      int t = __shfl_up(sc, o);
      if (lane >= o) sc += t;
    }
    if (lane == 63) ws[wave] = sc;
    __syncthreads();
    int wp = 0, tot = 0;
#pragma unroll
    for (int k = 0; k < 16; k++){ int w_ = ws[k]; if (k < wave) wp += w_; tot += w_; }
    if (i < n) offs[i] = base_s + wp + sc - v;
    __syncthreads();
    if (tid == 0) base_s += tot;
    __syncthreads();
  }
}

// ---------------- CSR scatter ----------------

__global__ void csr_kernel(const int* __restrict__ src, const int* __restrict__ dst,
                           const int* __restrict__ offs, int* cursor,
                           int* __restrict__ nsrc, int E){
  int e = blockIdx.x * 256 + threadIdx.x;
  if (e >= E) return;
  int d = dst[e];
  int p = atomicAdd(&cursor[d], 1);
  nsrc[offs[d] + p] = src[e];
}

// ---------------- aggregate-first: wave-per-dst, unpack-once inner loop ----------

__global__ __launch_bounds__(256) void aggx_kernel(
    const int* __restrict__ counts, const int* __restrict__ offs,
    const int* __restrict__ nsrc,
    const float2* __restrict__ sa, const float2* __restrict__ da,
    const float2* __restrict__ ese,
    const unsigned short* __restrict__ xb,
    unsigned short* __restrict__ xa1b, unsigned short* __restrict__ xa2b, int N){
  int wid = threadIdx.x >> 6, lane = threadIdx.x & 63;
  int d = blockIdx.x * 4 + wid;
  if (d >= N) return;
  float2 dad = da[d];
  int deg = counts[d], off = offs[d];
  float acc1[8] = {0,0,0,0,0,0,0,0}, acc2[8] = {0,0,0,0,0,0,0,0};
  float den1 = 0.f, den2 = 0.f;
  const unsigned short* Xb = xb + lane * 8;
  for (int base = 0; base < deg; base += 64){
    int i = base + lane;
    int s = 0; float x1 = 0.f, x2 = 0.f;
    if (i < deg){
      s = nsrc[off + i];
      float2 sas = sa[s];
      x1 = expf(leaky(sas.x + dad.x));
      x2 = expf(leaky(sas.y + dad.y));
    }
    den1 += x1; den2 += x2;
    int cnt = min(64, deg - base);
#pragma unroll 4
    for (int j = 0; j < cnt; j++){
      int sj = __shfl(s, j);
      float w1j = __shfl(x1, j);
      float w2j = __shfl(x2, j);
      int4 u = *(const int4*)(Xb + (size_t)sj * IN_C);
      float f[8];
      f[0] = __uint_as_float(((unsigned)u.x) << 16);
      f[1] = __uint_as_float(((unsigned)u.x) & 0xffff0000u);
      f[2] = __uint_as_float(((unsigned)u.y) << 16);
      f[3] = __uint_as_float(((unsigned)u.y) & 0xffff0000u);
      f[4] = __uint_as_float(((unsigned)u.z) << 16);
      f[5] = __uint_as_float(((unsigned)u.z) & 0xffff0000u);
      f[6] = __uint_as_float(((unsigned)u.w) << 16);
      f[7] = __uint_as_float(((unsigned)u.w) & 0xffff0000u);
#pragma unroll
      for (int c = 0; c < 8; c++){ acc1[c] += w1j * f[c]; acc2[c] += w2j * f[c]; }
    }
  }
  for (int o = 32; o; o >>= 1){
    den1 += __shfl_xor(den1, o);
    den2 += __shfl_xor(den2, o);
  }
  float2 es = ese[d];
  {
    int4 u = *(const int4*)(Xb + (size_t)d * IN_C);
    float f[8];
    f[0] = __uint_as_float(((unsigned)u.x) << 16);
    f[1] = __uint_as_float(((unsigned)u.x) & 0xffff0000u);
    f[2] = __uint_as_float(((unsigned)u.y) << 16);
    f[3] = __uint_as_float(((unsigned)u.y) & 0xffff0000u);
    f[4] = __uint_as_float(((unsigned)u.z) << 16);
    f[5] = __uint_as_float(((unsigned)u.z) & 0xffff0000u);
    f[6] = __uint_as_float(((unsigned)u.w) << 16);
    f[7] = __uint_as_float(((unsigned)u.w) & 0xffff0000u);
#pragma unroll
    for (int c = 0; c < 8; c++){ acc1[c] += es.x * f[c]; acc2[c] += es.y * f[c]; }
  }
  den1 += es.x; den2 += es.y;
  float inv1 = 1.f / den1, inv2 = 1.f / den2;
  size_t outb = (size_t)d * IN_C + lane * 8;
  int4 o1, o2;
  o1.x = (int)((unsigned)f2b(acc1[0]*inv1) | ((unsigned)f2b(acc1[1]*inv1) << 16));
  o1.y = (int)((unsigned)f2b(acc1[2]*inv1) | ((unsigned)f2b(acc1[3]*inv1) << 16));
  o1.z = (int)((unsigned)f2b(acc1[4]*inv1) | ((unsigned)f2b(acc1[5]*inv1) << 16));
  o1.w = (int)((unsigned)f2b(acc1[6]*inv1) | ((unsigned)f2b(acc1[7]*inv1) << 16));
  o2.x = (int)((unsigned)f2b(acc2[0]*inv2) | ((unsigned)f2b(acc2[1]*inv2) << 16));
  o2.y = (int)((unsigned)f2b(acc2[2]*inv2) | ((unsigned)f2b(acc2[3]*inv2) << 16));
  o2.z = (int)((unsigned)f2b(acc2[4]*inv2) | ((unsigned)f2b(acc2[5]*inv2) << 16));
  o2.w = (int)((unsigned)f2b(acc2[6]*inv2) | ((unsigned)f2b(acc2[7]*inv2) << 16));
  *(int4*)(xa1b + outb) = o1;
  *(int4*)(xa2b + outb) = o2;
}

// ---------------- fused GEMM-H: exact R0 structure (frozen; best measured) -------

__global__ __launch_bounds__(256) void gemmh_kernel(const unsigned short* __restrict__ A1,
                                                    const unsigned short* __restrict__ A2,
                                                    const unsigned short* __restrict__ BT,
                                                    const float* __restrict__ b1,
                                                    const float* __restrict__ b2,
                                                    const float* __restrict__ prelu_a,
                                                    unsigned short* __restrict__ hsum,
                                                    unsigned short* __restrict__ hdiff,
                                                    int M, int Mtiles, int perx){
  const int bid = blockIdx.x;
  const int xcd = bid & 7;
  const int li = bid >> 3;
  const int bn_t = li & 7;
  const int bm_t = xcd * perx + (li >> 3);
  if (bm_t >= Mtiles) return;
  const int bm = bm_t * 64, bn = bn_t * 128;
  __shared__ unsigned short Al[64 * 32];   // 4 KB
  __shared__ unsigned short Bl[128 * 32];  // 8 KB
  const int t = threadIdx.x;
  const int lane = t & 63, wid = t >> 6;
  const int wj = wid;
  const int l16 = lane & 15, q = lane >> 4;
  const int lch = (lane & 3) * 8;
  f32x4 acc1[4][2] = {};
  f32x4 acc2[4][2] = {};
  const int arow = bm + wid * 16 + (lane >> 2);
  const int brow0 = bn + wid * 32 + (lane >> 2);
  const int ga = min(arow, M - 1);
  const unsigned short* pa1 = A1 + (size_t)ga * IN_C + lch;
  const unsigned short* pa2 = A2 + (size_t)ga * IN_C + lch;
  const unsigned short* pb0 = BT + (size_t)brow0 * IN_C + lch;
  const unsigned short* pb1 = BT + (size_t)(brow0 + 16) * IN_C + lch;
  const size_t boff2 = (size_t)OUT_C * IN_C;
  // ---- GEMM 1 ----
  for (int k0 = 0; k0 < IN_C; k0 += 32){
    GLOAD_LDS16(pa1 + k0, &Al[(wid * 16) * 32]);
    GLOAD_LDS16(pb0 + k0, &Bl[(wid * 32) * 32]);
    GLOAD_LDS16(pb1 + k0, &Bl[(wid * 32 + 16) * 32]);
    __syncthreads();
    frag8 af[4], bf[2];
#pragma unroll
    for (int mi = 0; mi < 4; mi++) af[mi] = *(const frag8*)&Al[(mi*16 + l16) * 32 + q*8];
#pragma unroll
    for (int nj = 0; nj < 2; nj++) bf[nj] = *(const frag8*)&Bl[(wj*32 + nj*16 + l16) * 32 + q*8];
#pragma unroll
    for (int mi = 0; mi < 4; mi++)
#pragma unroll
      for (int nj = 0; nj < 2; nj++)
        acc1[mi][nj] = __builtin_amdgcn_mfma_f32_16x16x32_bf16(af[mi], bf[nj], acc1[mi][nj], 0, 0, 0);
    __syncthreads();
  }
  // ---- GEMM 2 ----
  for (int k0 = 0; k0 < IN_C; k0 += 32){
    GLOAD_LDS16(pa2 + k0, &Al[(wid * 16) * 32]);
    GLOAD_LDS16(pb0 + boff2 + k0, &Bl[(wid * 32) * 32]);
    GLOAD_LDS16(pb1 + boff2 + k0, &Bl[(wid * 32 + 16) * 32]);
    __syncthreads();
    frag8 af[4], bf[2];
#pragma unroll
    for (int mi = 0; mi < 4; mi++) af[mi] = *(const frag8*)&Al[(mi*16 + l16) * 32 + q*8];
#pragma unroll
    for (int nj = 0; nj < 2; nj++) bf[nj] = *(const frag8*)&Bl[(wj*32 + nj*16 + l16) * 32 + q*8];
#pragma unroll
    for (int mi = 0; mi < 4; mi++)
#pragma unroll
      for (int nj = 0; nj < 2; nj++)
        acc2[mi][nj] = __builtin_amdgcn_mfma_f32_16x16x32_bf16(af[mi], bf[nj], acc2[mi][nj], 0, 0, 0);
    __syncthreads();
  }
  float pa = prelu_a[0];
#pragma unroll
  for (int mi = 0; mi < 4; mi++){
#pragma unroll
    for (int r = 0; r < 4; r++){
      int row = bm + mi*16 + q*4 + r;
      if (row >= M) continue;
#pragma unroll
      for (int nj = 0; nj < 2; nj++){
        int col = bn + wj*32 + nj*16 + l16;
        float v1 = acc1[mi][nj][r] + b1[col];
        v1 = v1 >= 0.f ? v1 : pa * v1;
        float v2 = acc2[mi][nj][r] + b2[col];
        v2 = v2 >= 0.f ? v2 : pa * v2;
        size_t idx = (size_t)row * OUT_C + col;
        hsum[idx]  = f2b(v1 + v2);
        hdiff[idx] = f2b(v1 - v2);
      }
    }
  }
}

// ---------------- GEMM2: exact R0 structure (frozen) ----------------

__global__ __launch_bounds__(256) void gemm2_kernel(const unsigned short* __restrict__ A,
                                                    const unsigned short* __restrict__ BT,
                                                    const float* __restrict__ bp1,
                                                    float* __restrict__ colsum,
                                                    int M, int Mtiles, int perx){
  const int bid = blockIdx.x;
  const int xcd = bid & 7;
  const int li = bid >> 3;
  const int bn_t = li & 7;
  const int bm_t = xcd * perx + (li >> 3);
  if (bm_t >= Mtiles) return;
  const int bm = bm_t * 64, bn = bn_t * 128;
  __shared__ unsigned short Al[64 * 32];
  __shared__ unsigned short Bl[128 * 32];
  __shared__ float cs[128];
  const int t = threadIdx.x;
  const int lane = t & 63, wid = t >> 6;
  const int wj = wid;
  const int l16 = lane & 15, q = lane >> 4;
  const int lch = (lane & 3) * 8;
  if (t < 128) cs[t] = 0.f;
  f32x4 acc[4][2] = {};
  const int arow = bm + wid * 16 + (lane >> 2);
  const int brow0 = bn + wid * 32 + (lane >> 2);
  const int ga = min(arow, M - 1);
  const unsigned short* pa = A + (size_t)ga * OUT_C + lch;
  const unsigned short* pb0 = BT + (size_t)brow0 * OUT_C + lch;
  const unsigned short* pb1 = BT + (size_t)(brow0 + 16) * OUT_C + lch;
  for (int k0 = 0; k0 < OUT_C; k0 += 32){
    GLOAD_LDS16(pa + k0, &Al[(wid * 16) * 32]);
    GLOAD_LDS16(pb0 + k0, &Bl[(wid * 32) * 32]);
    GLOAD_LDS16(pb1 + k0, &Bl[(wid * 32 + 16) * 32]);
    __syncthreads();
    frag8 af[4], bf[2];
#pragma unroll
    for (int mi = 0; mi < 4; mi++) af[mi] = *(const frag8*)&Al[(mi*16 + l16) * 32 + q*8];
#pragma unroll
    for (int nj = 0; nj < 2; nj++) bf[nj] = *(const frag8*)&Bl[(wj*32 + nj*16 + l16) * 32 + q*8];
#pragma unroll
    for (int mi = 0; mi < 4; mi++)
#pragma unroll
      for (int nj = 0; nj < 2; nj++)
        acc[mi][nj] = __builtin_amdgcn_mfma_f32_16x16x32_bf16(af[mi], bf[nj], acc[mi][nj], 0, 0, 0);
    __syncthreads();
  }
#pragma unroll
  for (int nj = 0; nj < 2; nj++){
    int col = bn + wj*32 + nj*16 + l16;
    float bias = bp1[col];
    float p = 0.f;
#pragma unroll
    for (int mi = 0; mi < 4; mi++){
#pragma unroll
      for (int r = 0; r < 4; r++){
        int row = bm + mi*16 + q*4 + r;
        float tv = tanhf(acc[mi][nj][r] + bias);
        if (row < M) p += tv;
      }
    }
    p += __shfl_xor(p, 16);
    p += __shfl_xor(p, 32);
    if (q == 0) atomicAdd(&cs[wj*32 + nj*16 + l16], p);
  }
  __syncthreads();
  if (t < 128) atomicAdd(&colsum[bn + t], cs[t]);
}

// ---------------- semantic attention tail ----------------

__global__ void wproj_kernel(const float* __restrict__ colsum, const float* __restrict__ Wp2,
                             float* __restrict__ wv){
  int o = blockIdx.x * 256 + threadIdx.x;
  int c0 = blockIdx.y * 128;
  float acc = 0.f;
  for (int c = c0; c < c0 + 128; c++) acc += colsum[c] * Wp2[(size_t)c * OUT_C + o];
  atomicAdd(&wv[o], acc);
}

__global__ __launch_bounds__(1024) void softmax_kernel(const float* __restrict__ wv,
                                                       float* __restrict__ att, float invN){
  int o = threadIdx.x;
  __shared__ float red[1024];
  float w = wv[o] * invN;
  red[o] = w; __syncthreads();
  for (int s = 512; s > 0; s >>= 1){ if (o < s) red[o] = fmaxf(red[o], red[o + s]); __syncthreads(); }
  float m = red[0]; __syncthreads();
  float e = expf(w - m);
  red[o] = e; __syncthreads();
  for (int s = 512; s > 0; s >>= 1){ if (o < s) red[o] += red[o + s]; __syncthreads(); }
  att[o] = e / red[0];
}

// pure stream (82 MB, zero reuse) -> nontemporal loads+stores keep it out of L2
// (NT builtins need clang ext-vector types, not HIP_vector_type int4)

__global__ void combine_kernel(const float* __restrict__ att, const unsigned short* __restrict__ hs,
                               const unsigned short* __restrict__ hd, float* __restrict__ out, int total8){
  int i = blockIdx.x * 256 + threadIdx.x;
  if (i >= total8) return;
  int colb = (i & 127) * 8;
  i32x4 us = __builtin_nontemporal_load(((const i32x4*)hs) + i);
  i32x4 ud = __builtin_nontemporal_load(((const i32x4*)hd) + i);
  float4 a0 = *(const float4*)(att + colb);
  float4 a1 = *(const float4*)(att + colb + 4);
  float o[8]; float sv, dv;
  sv = __uint_as_float(((unsigned)us[0]) << 16);         dv = __uint_as_float(((unsigned)ud[0]) << 16);
  o[0] = 0.5f * sv + (a0.x - 0.5f) * dv;
  sv = __uint_as_float(((unsigned)us[0]) & 0xffff0000u); dv = __uint_as_float(((unsigned)ud[0]) & 0xffff0000u);
  o[1] = 0.5f * sv + (a0.y - 0.5f) * dv;
  sv = __uint_as_float(((unsigned)us[1]) << 16);         dv = __uint_as_float(((unsigned)ud[1]) << 16);
  o[2] = 0.5f * sv + (a0.z - 0.5f) * dv;
  sv = __uint_as_float(((unsigned)us[1]) & 0xffff0000u); dv = __uint_as_float(((unsigned)ud[1]) & 0xffff0000u);
  o[3] = 0.5f * sv + (a0.w - 0.5f) * dv;
  sv = __uint_as_float(((unsigned)us[2]) << 16);         dv = __uint_as_float(((unsigned)ud[2]) << 16);
  o[4] = 0.5f * sv + (a1.x - 0.5f) * dv;
  sv = __uint_as_float(((unsigned)us[2]) & 0xffff0000u); dv = __uint_as_float(((unsigned)ud[2]) & 0xffff0000u);
  o[5] = 0.5f * sv + (a1.y - 0.5f) * dv;
  sv = __uint_as_float(((unsigned)us[3]) << 16);         dv = __uint_as_float(((unsigned)ud[3]) << 16);
  o[6] = 0.5f * sv + (a1.z - 0.5f) * dv;
  sv = __uint_as_float(((unsigned)us[3]) & 0xffff0000u); dv = __uint_as_float(((unsigned)ud[3]) & 0xffff0000u);
  o[7] = 0.5f * sv + (a1.w - 0.5f) * dv;
  f32x4 f0; f0[0] = o[0]; f0[1] = o[1]; f0[2] = o[2]; f0[3] = o[3];
  f32x4 f1; f1[0] = o[4]; f1[1] = o[5]; f1[2] = o[6]; f1[3] = o[7];
  __builtin_nontemporal_store(f0, (f32x4*)(out + (size_t)i * 8));
  __builtin_nontemporal_store(f1, (f32x4*)(out + (size_t)i * 8 + 4));
}

// ---------------- launch ----------------

extern "C" void kernel_launch(void* const* d_in, const int* in_sizes, int n_in,
                              void* d_out, int out_size, void* d_ws, size_t ws_size,
                              hipStream_t stream){
  const float* x      = (const float*)d_in[0];
  const int*   edge   = (const int*)d_in[1];
  const float* W1     = (const float*)d_in[2];
  const float* a_src1 = (const float*)d_in[3];
  const float* a_dst1 = (const float*)d_in[4];
  const float* b1     = (const float*)d_in[5];
  const float* W2     = (const float*)d_in[6];
  const float* a_src2 = (const float*)d_in[7];
  const float* a_dst2 = (const float*)d_in[8];
  const float* b2     = (const float*)d_in[9];
  const float* prelu_a= (const float*)d_in[10];
  const float* Wp1    = (const float*)d_in[11];
  const float* bp1    = (const float*)d_in[12];
  const float* Wp2    = (const float*)d_in[13];
  const int N = in_sizes[0] / IN_C;
  const int E = in_sizes[1] / 2;
  const int* srcArr = edge;
  const int* dstArr = edge + E;

  char* ws = (char*)d_ws;
  size_t o = 0;
  auto alloc = [&](size_t b) -> char* {
    char* p = ws + o;
    o = (o + b + 255) & ~(size_t)255;
    return p;
  };
  unsigned short* xb    = (unsigned short*)alloc((size_t)N * IN_C * 2);
  unsigned short* WT    = (unsigned short*)alloc((size_t)NC2 * IN_C * 2);
  unsigned short* Wp1T  = (unsigned short*)alloc((size_t)OUT_C * OUT_C * 2);
  unsigned short* xa1b  = (unsigned short*)alloc((size_t)N * IN_C * 2);
  unsigned short* xa2b  = (unsigned short*)alloc((size_t)N * IN_C * 2);
  unsigned short* hsum  = (unsigned short*)alloc((size_t)N * OUT_C * 2);
  unsigned short* hdiff = (unsigned short*)alloc((size_t)N * OUT_C * 2);
  float*          uv    = (float*)alloc(4 * IN_C * 4);
  float2*         sa    = (float2*)alloc((size_t)N * 8);
  float2*         da    = (float2*)alloc((size_t)N * 8);
  float2*         ese   = (float2*)alloc((size_t)N * 8);
  int*            counts= (int*)alloc((size_t)N * 4);
  int*            offs  = (int*)alloc((size_t)(N + 1) * 4);
  int*            cursor= (int*)alloc((size_t)N * 4);
  int*            nsrc  = (int*)alloc((size_t)E * 4);
  float*          colsum= (float*)alloc(OUT_C * 4);
  float*          wv    = (float*)alloc(OUT_C * 4);
  float*          att   = (float*)alloc(OUT_C * 4);

  const int Mtiles = (N + 63) / 64;
  const int perx = (Mtiles + 7) / 8;
  const int gemmgrid = 8 * perx * 8;
  const int zblocks = (N + 255) / 256;
  const int eblocks = (E + 255) / 256;

  prep_kernel<<<2560 + zblocks, 256, 0, stream>>>(W1, W2, Wp1, a_src1, a_dst1, a_src2, a_dst2,
                                                  WT, Wp1T, uv, counts, cursor, N);
  alphahist_kernel<<<N + eblocks, 256, 0, stream>>>(x, uv, dstArr, xb, sa, da, ese,
                                                    counts, colsum, wv, N, E);
  scan_kernel<<<1, 1024, 0, stream>>>(counts, offs, N);
  csr_kernel<<<eblocks, 256, 0, stream>>>(srcArr, dstArr, offs, cursor, nsrc, E);
  aggx_kernel<<<(N + 3) / 4, 256, 0, stream>>>(counts, offs, nsrc, sa, da, ese,
                                               xb, xa1b, xa2b, N);
  gemmh_kernel<<<gemmgrid, 256, 0, stream>>>(xa1b, xa2b, WT, b1, b2, prelu_a,
                                             hsum, hdiff, N, Mtiles, perx);
  gemm2_kernel<<<gemmgrid, 256, 0, stream>>>(hsum, Wp1T, bp1, colsum, N, Mtiles, perx);
  wproj_kernel<<<dim3(4, 8), 256, 0, stream>>>(colsum, Wp2, wv);
  softmax_kernel<<<1, 1024, 0, stream>>>(wv, att, 1.0f / (float)N);
  combine_kernel<<<(N * OUT_C / 8 + 255) / 256, 256, 0, stream>>>(att, hsum, hdiff, (float*)d_out,
                                                                  N * OUT_C / 8);
}